// Round 10
// baseline (538.467 us; speedup 1.0000x reference)
//
#include <hip/hip_runtime.h>
#include <math.h>

#define NB 32
#define CIN 32
#define DIM 32
#define KK 5
#define VALID 17
#define CVOL (VALID*VALID*VALID)   // 4913
#define RSS 38                     // slab row stride in shorts: col = iw (0..31) + 6 pad
#define ROWS 37                    // row = ih+2; zeros at 0,1,34,35,36
#define PLN 7                      // planes for a d-pair: ids 4p-2 .. 4p+4
#define SLABSH (PLN*ROWS*RSS)      // 9842 shorts
#define SLABPAD 9848               // padded to uint4 multiple -> 19696 B -> 8 blocks/CU

// ws layout (floats): [0,4000) w_eff ; [4000] B ; [4096, ...) C partials [nsplit][32][4913]

__device__ __forceinline__ unsigned int pack2bf(float a, float b) {   // RNE pack
    unsigned int ua = __float_as_uint(a);
    ua += 0x7FFFu + ((ua >> 16) & 1u);
    unsigned int ub = __float_as_uint(b);
    ub += 0x7FFFu + ((ub >> 16) & 1u);
    return (ua >> 16) | (ub & 0xFFFF0000u);
}
__device__ __forceinline__ float bflo(unsigned int u) { return __uint_as_float(u << 16); }
__device__ __forceinline__ float bfhi(unsigned int u) { return __uint_as_float(u & 0xFFFF0000u); }

__global__ __launch_bounds__(256) void prep_kernel(const float* __restrict__ weight,
                                                   const float* __restrict__ bias,
                                                   float* __restrict__ ws) {
    int idx = blockIdx.x * 256 + threadIdx.x;
    if (idx < 4000) {
        float s = 0.f;
        #pragma unroll 8
        for (int co = 0; co < 64; ++co) s += weight[co * 4000 + idx];
        ws[idx] = s;
    }
    if (idx == 0) {
        float b = 0.f;
        for (int i = 0; i < 64; ++i) b += bias[i];
        ws[4000] = b;
    }
}

// Block = (split s, n, d-pair p). 128 threads: dq = tid>>6 (wave), hg = (tid>>3)&7, wq = tid&7.
// Thread outputs: d = 2p+dq; h = 2hg,2hg+1 (hg=7: 14,15,16); w = 2wq+1, 2wq+2 (+ w=0 if wq==0).
// Slab bf16: [pi 7][row 37][RSS 38]; pi = id-(4p-2); row = ih+2; short col = iw.
// T14 async-stage: next cin's 14 float4 in pf[]; stage phase = pack+ds_write_b64 only.
__global__ __launch_bounds__(128, 4) void conv_kernel(const float* __restrict__ x,
                                                      const float* __restrict__ weff,
                                                      float* __restrict__ C,
                                                      int cpS) {
    __shared__ __align__(16) unsigned short slabS[SLABPAD];
    const int b = blockIdx.x;
    const int s = b / (NB * 9);
    const int rem = b - s * (NB * 9);
    const int n = rem / 9;
    const int p = rem - n * 9;
    const int tid = threadIdx.x;
    const int dq = tid >> 6;
    const int hg = (tid >> 3) & 7;
    const int wq = tid & 7;
    const int d  = 2 * p + dq;
    const bool dok = (d < VALID);
    const bool tall = (hg == 7);      // 3rd h-row
    const bool w0t  = (wq == 0);      // also computes w=0

    // zero slab once; pad rows/cols never rewritten
    uint4* s4 = (uint4*)slabS;
    for (int t = tid; t < SLABPAD / 8; t += 128) s4[t] = make_uint4(0u, 0u, 0u, 0u);

    const int id0 = 4 * p - 2;
    const int cin0 = s * cpS;

    float4 pf[14];
    {
        const float* xn = x + (((size_t)n * CIN + cin0) * DIM) * DIM * DIM;
        #pragma unroll
        for (int i = 0; i < 14; ++i) {
            int g  = tid + 128 * i;
            int pi = g >> 8;
            int rr = (g >> 3) & 31;
            int c4 = g & 7;
            int id = id0 + pi;
            bool ok = (id >= 0 && id < DIM);
            pf[i] = ok ? *(const float4*)&xn[((size_t)id * DIM + rr) * DIM + 4 * c4]
                       : make_float4(0.f, 0.f, 0.f, 0.f);
        }
    }
    __syncthreads();

    float acc[3][2] = {{0.f,0.f},{0.f,0.f},{0.f,0.f}};
    float accw0[3]  = {0.f, 0.f, 0.f};

    for (int ci = 0; ci < cpS; ++ci) {
        // stage: f32 -> bf16 pack + aligned ds_write_b64 (zeros for OOB planes)
        #pragma unroll
        for (int i = 0; i < 14; ++i) {
            int g  = tid + 128 * i;
            int pi = g >> 8;
            int rr = (g >> 3) & 31;
            int c4 = g & 7;
            uint2 u = make_uint2(pack2bf(pf[i].x, pf[i].y), pack2bf(pf[i].z, pf[i].w));
            *(uint2*)&slabS[(pi * ROWS + rr + 2) * RSS + 4 * c4] = u;
        }
        __syncthreads();

        // issue next cin's global loads; complete under compute
        if (ci + 1 < cpS) {
            const float* xn = x + (((size_t)n * CIN + cin0 + ci + 1) * DIM) * DIM * DIM;
            #pragma unroll
            for (int i = 0; i < 14; ++i) {
                int g  = tid + 128 * i;
                int pi = g >> 8;
                int rr = (g >> 3) & 31;
                int c4 = g & 7;
                int id = id0 + pi;
                bool ok = (id >= 0 && id < DIM);
                pf[i] = ok ? *(const float4*)&xn[((size_t)id * DIM + rr) * DIM + 4 * c4]
                           : make_float4(0.f, 0.f, 0.f, 0.f);
            }
        }

        const float* wb = weff + (cin0 + ci) * 125;
        #pragma unroll
        for (int kd = 0; kd < KK; ++kd) {
            const unsigned short* plane = slabS + (2 * dq + kd) * (ROWS * RSS);
            #pragma unroll
            for (int j = 0; j < 9; ++j) {
                if (j <= 6 || tall) {
                    const unsigned short* rp = plane + (4 * hg + j) * RSS + 4 * wq;
                    const uint2 A  = *(const uint2*)rp;        // shorts 4wq..4wq+3
                    const uint2 Bv = *(const uint2*)(rp + 4);  // shorts 4wq+4..4wq+7
                    const float x0 = bflo(A.x),  x1 = bfhi(A.x);
                    const float x2 = bflo(A.y),  x3 = bfhi(A.y);
                    const float x4 = bflo(Bv.x), x5 = bfhi(Bv.x);
                    const float x6 = bflo(Bv.y);
                    #pragma unroll
                    for (int hh = 0; hh < 3; ++hh) {
                        const int kh = j - 2 * hh;
                        if (kh >= 0 && kh < KK) {
                            if (hh < 2 || tall) {
                                const float w0 = wb[kd * 25 + kh * 5 + 0];
                                const float w1 = wb[kd * 25 + kh * 5 + 1];
                                const float w2 = wb[kd * 25 + kh * 5 + 2];
                                const float w3 = wb[kd * 25 + kh * 5 + 3];
                                const float w4 = wb[kd * 25 + kh * 5 + 4];
                                acc[hh][0] = fmaf(w0, x0, acc[hh][0]);
                                acc[hh][1] = fmaf(w0, x2, acc[hh][1]);
                                acc[hh][0] = fmaf(w1, x1, acc[hh][0]);
                                acc[hh][1] = fmaf(w1, x3, acc[hh][1]);
                                acc[hh][0] = fmaf(w2, x2, acc[hh][0]);
                                acc[hh][1] = fmaf(w2, x4, acc[hh][1]);
                                acc[hh][0] = fmaf(w3, x3, acc[hh][0]);
                                acc[hh][1] = fmaf(w3, x5, acc[hh][1]);
                                acc[hh][0] = fmaf(w4, x4, acc[hh][0]);
                                acc[hh][1] = fmaf(w4, x6, acc[hh][1]);
                                if (w0t) {   // w=0: kw 2,3,4 hit iw 0,1,2
                                    accw0[hh] = fmaf(w2, x0, accw0[hh]);
                                    accw0[hh] = fmaf(w3, x1, accw0[hh]);
                                    accw0[hh] = fmaf(w4, x2, accw0[hh]);
                                }
                            }
                        }
                    }
                }
            }
        }
        __syncthreads();
    }

    if (dok) {
        float* Cn = C + ((size_t)s * NB + n) * CVOL + (size_t)d * (VALID * VALID);
        #pragma unroll
        for (int hh = 0; hh < 3; ++hh) {
            if (hh < 2 || tall) {
                int h = 2 * hg + hh;
                Cn[h * VALID + 2 * wq + 1] = acc[hh][0];
                Cn[h * VALID + 2 * wq + 2] = acc[hh][1];
                if (w0t) Cn[h * VALID] = accw0[hh];
            }
        }
    }
}

// Blocks 0..863: one wave per active cell (n, i<3, j<3, k<3); lane = p1-subcell;
// fused nsplit reduction; butterfly sum. Blocks 864..988: constant fill.
__global__ __launch_bounds__(64) void pool_kernel(const float* __restrict__ C,
                                                  const float* __restrict__ wsB,
                                                  float* __restrict__ out,
                                                  int nsplit) {
    const int b = blockIdx.x;
    const int l = threadIdx.x;
    const float B = wsB[0];

    if (b < 864) {
        const int n = b / 27;
        const int cell = b - n * 27;
        const int ci = cell / 9, cj = (cell / 3) % 3, ck = cell % 3;
        float v = 0.f;
        if (l < 27) {
            const int da = l / 9, db = (l / 3) % 3, dc = l % 3;
            const int pz = 3 * ci + da, py = 3 * cj + db, px = 3 * ck + dc;
            const float* Cn = C + (size_t)n * CVOL;
            float m = -INFINITY;
            #pragma unroll
            for (int dz = 0; dz < 2; ++dz)
            #pragma unroll
            for (int dy = 0; dy < 2; ++dy)
            #pragma unroll
            for (int dx = 0; dx < 2; ++dx) {
                int z = 2 * pz + dz, y = 2 * py + dy, xx = 2 * px + dx;
                float t;
                if (z < VALID && y < VALID && xx < VALID) {
                    size_t off = ((size_t)z * VALID + y) * VALID + xx;
                    float sum = 0.f;
                    for (int ss = 0; ss < nsplit; ++ss)
                        sum += Cn[(size_t)ss * NB * CVOL + off];
                    t = sum + B;
                } else {
                    t = B;
                }
                m = fmaxf(m, t);
            }
            v = m;
        }
        #pragma unroll
        for (int off = 32; off > 0; off >>= 1) v += __shfl_xor(v, off, 64);
        if (l == 0) out[n * 1000 + ci * 100 + cj * 10 + ck] = v;
    } else {
        const int fb = b - 864;           // 0..124
        #pragma unroll
        for (int t = 0; t < 4; ++t) {
            int idx = fb * 256 + 64 * t + l;
            if (idx < 32000) {
                int r = idx % 1000;
                int i = r / 100, j = (r / 10) % 10, k = r % 10;
                if (i >= 3 || j >= 3 || k >= 3) out[idx] = 27.f * B;
            }
        }
    }
}

extern "C" void kernel_launch(void* const* d_in, const int* in_sizes, int n_in,
                              void* d_out, int out_size, void* d_ws, size_t ws_size,
                              hipStream_t stream) {
    const float* x      = (const float*)d_in[0];
    const float* weight = (const float*)d_in[1];
    const float* bias   = (const float*)d_in[2];
    float* out = (float*)d_out;
    float* ws  = (float*)d_ws;
    float* weff = ws;
    float* wsB  = ws + 4000;
    float* C    = ws + 4096;

    int nsplit = 1;
    if      (ws_size >= (size_t)(4096 + 8 * NB * CVOL) * 4) nsplit = 8;
    else if (ws_size >= (size_t)(4096 + 4 * NB * CVOL) * 4) nsplit = 4;
    else if (ws_size >= (size_t)(4096 + 2 * NB * CVOL) * 4) nsplit = 2;
    int cpS = CIN / nsplit;

    prep_kernel<<<dim3(16), dim3(256), 0, stream>>>(weight, bias, ws);
    conv_kernel<<<dim3(nsplit * NB * 9), dim3(128), 0, stream>>>(x, weff, C, cpS);
    pool_kernel<<<dim3(989), dim3(64), 0, stream>>>(C, wsB, out, nsplit);
}

// Round 11
// 132.005 us; speedup vs baseline: 4.0791x; 4.0791x over previous
//
#include <hip/hip_runtime.h>
#include <math.h>

#define NB 32
#define CIN 32
#define DIM 32
#define KK 5
#define VALID 17
#define CVOL (VALID*VALID*VALID)   // 4913
#define RSS 38                     // slab row stride in shorts: col = iw (0..31) + 6 pad
#define ROWS 37                    // row = ih+2; zeros at 0,1,34,35,36
#define PLN 7                      // planes for a d-pair: ids 4p-2 .. 4p+4
#define SLABSH (PLN*ROWS*RSS)      // 9842 shorts
#define SLABPAD 9848               // padded to uint4 multiple -> 19696 B -> 8 blocks/CU

// ws layout (floats): [0,4000) w_eff ; [4000] B ; [4096, ...) C partials [nsplit][32][4913]

__device__ __forceinline__ unsigned int pack2bf(float a, float b) {   // RNE pack
    unsigned int ua = __float_as_uint(a);
    ua += 0x7FFFu + ((ua >> 16) & 1u);
    unsigned int ub = __float_as_uint(b);
    ub += 0x7FFFu + ((ub >> 16) & 1u);
    return (ua >> 16) | (ub & 0xFFFF0000u);
}
__device__ __forceinline__ float bflo(unsigned int u) { return __uint_as_float(u << 16); }
__device__ __forceinline__ float bfhi(unsigned int u) { return __uint_as_float(u & 0xFFFF0000u); }

__global__ __launch_bounds__(256) void prep_kernel(const float* __restrict__ weight,
                                                   const float* __restrict__ bias,
                                                   float* __restrict__ ws) {
    int idx = blockIdx.x * 256 + threadIdx.x;
    if (idx < 4000) {
        float s = 0.f;
        #pragma unroll 8
        for (int co = 0; co < 64; ++co) s += weight[co * 4000 + idx];
        ws[idx] = s;
    }
    if (idx == 0) {
        float b = 0.f;
        for (int i = 0; i < 64; ++i) b += bias[i];
        ws[4000] = b;
    }
}

// Block = (split s, n, d-pair p). 128 threads: dq = tid>>6 (wave), hg = (tid>>3)&7, wq = tid&7.
// Thread outputs: d = 2p+dq; h = 2hg,2hg+1 (hg=7: 14,15,16); w = 2wq+1, 2wq+2 (+ w=0 if wq==0).
// Slab bf16: [pi 7][row 37][RSS 38]; pi = id-(4p-2); row = ih+2; short col = iw.
// T14 async-stage: next cin's 14 float4 in pf[]; stage phase = pack+ds_write_b64 only.
// NOTE: no min-waves launch-bound — (128,4) forced VGPR=64 and spilled pf[] to scratch
// (546 MB fetch / 837 MB write, 6x slowdown, round 10).
__global__ __launch_bounds__(128) void conv_kernel(const float* __restrict__ x,
                                                   const float* __restrict__ weff,
                                                   float* __restrict__ C,
                                                   int cpS) {
    __shared__ __align__(16) unsigned short slabS[SLABPAD];
    const int b = blockIdx.x;
    const int s = b / (NB * 9);
    const int rem = b - s * (NB * 9);
    const int n = rem / 9;
    const int p = rem - n * 9;
    const int tid = threadIdx.x;
    const int dq = tid >> 6;
    const int hg = (tid >> 3) & 7;
    const int wq = tid & 7;
    const int d  = 2 * p + dq;
    const bool dok = (d < VALID);
    const bool tall = (hg == 7);      // 3rd h-row
    const bool w0t  = (wq == 0);      // also computes w=0

    // zero slab once; pad rows/cols never rewritten
    uint4* s4 = (uint4*)slabS;
    for (int t = tid; t < SLABPAD / 8; t += 128) s4[t] = make_uint4(0u, 0u, 0u, 0u);

    const int id0 = 4 * p - 2;
    const int cin0 = s * cpS;

    float4 pf[14];
    {
        const float* xn = x + (((size_t)n * CIN + cin0) * DIM) * DIM * DIM;
        #pragma unroll
        for (int i = 0; i < 14; ++i) {
            int g  = tid + 128 * i;
            int pi = g >> 8;
            int rr = (g >> 3) & 31;
            int c4 = g & 7;
            int id = id0 + pi;
            bool ok = (id >= 0 && id < DIM);
            pf[i] = ok ? *(const float4*)&xn[((size_t)id * DIM + rr) * DIM + 4 * c4]
                       : make_float4(0.f, 0.f, 0.f, 0.f);
        }
    }
    __syncthreads();

    float acc[3][2] = {{0.f,0.f},{0.f,0.f},{0.f,0.f}};
    float accw0[3]  = {0.f, 0.f, 0.f};

    for (int ci = 0; ci < cpS; ++ci) {
        // stage: f32 -> bf16 pack + aligned ds_write_b64 (zeros for OOB planes)
        #pragma unroll
        for (int i = 0; i < 14; ++i) {
            int g  = tid + 128 * i;
            int pi = g >> 8;
            int rr = (g >> 3) & 31;
            int c4 = g & 7;
            uint2 u = make_uint2(pack2bf(pf[i].x, pf[i].y), pack2bf(pf[i].z, pf[i].w));
            *(uint2*)&slabS[(pi * ROWS + rr + 2) * RSS + 4 * c4] = u;
        }
        __syncthreads();

        // issue next cin's global loads; complete under compute
        if (ci + 1 < cpS) {
            const float* xn = x + (((size_t)n * CIN + cin0 + ci + 1) * DIM) * DIM * DIM;
            #pragma unroll
            for (int i = 0; i < 14; ++i) {
                int g  = tid + 128 * i;
                int pi = g >> 8;
                int rr = (g >> 3) & 31;
                int c4 = g & 7;
                int id = id0 + pi;
                bool ok = (id >= 0 && id < DIM);
                pf[i] = ok ? *(const float4*)&xn[((size_t)id * DIM + rr) * DIM + 4 * c4]
                           : make_float4(0.f, 0.f, 0.f, 0.f);
            }
        }

        const float* wb = weff + (cin0 + ci) * 125;
        #pragma unroll
        for (int kd = 0; kd < KK; ++kd) {
            const unsigned short* plane = slabS + (2 * dq + kd) * (ROWS * RSS);
            #pragma unroll
            for (int j = 0; j < 9; ++j) {
                if (j <= 6 || tall) {
                    const unsigned short* rp = plane + (4 * hg + j) * RSS + 4 * wq;
                    const uint2 A  = *(const uint2*)rp;        // shorts 4wq..4wq+3
                    const uint2 Bv = *(const uint2*)(rp + 4);  // shorts 4wq+4..4wq+7
                    const float x0 = bflo(A.x),  x1 = bfhi(A.x);
                    const float x2 = bflo(A.y),  x3 = bfhi(A.y);
                    const float x4 = bflo(Bv.x), x5 = bfhi(Bv.x);
                    const float x6 = bflo(Bv.y);
                    #pragma unroll
                    for (int hh = 0; hh < 3; ++hh) {
                        const int kh = j - 2 * hh;
                        if (kh >= 0 && kh < KK) {
                            if (hh < 2 || tall) {
                                const float w0 = wb[kd * 25 + kh * 5 + 0];
                                const float w1 = wb[kd * 25 + kh * 5 + 1];
                                const float w2 = wb[kd * 25 + kh * 5 + 2];
                                const float w3 = wb[kd * 25 + kh * 5 + 3];
                                const float w4 = wb[kd * 25 + kh * 5 + 4];
                                acc[hh][0] = fmaf(w0, x0, acc[hh][0]);
                                acc[hh][1] = fmaf(w0, x2, acc[hh][1]);
                                acc[hh][0] = fmaf(w1, x1, acc[hh][0]);
                                acc[hh][1] = fmaf(w1, x3, acc[hh][1]);
                                acc[hh][0] = fmaf(w2, x2, acc[hh][0]);
                                acc[hh][1] = fmaf(w2, x4, acc[hh][1]);
                                acc[hh][0] = fmaf(w3, x3, acc[hh][0]);
                                acc[hh][1] = fmaf(w3, x5, acc[hh][1]);
                                acc[hh][0] = fmaf(w4, x4, acc[hh][0]);
                                acc[hh][1] = fmaf(w4, x6, acc[hh][1]);
                                if (w0t) {   // w=0: kw 2,3,4 hit iw 0,1,2
                                    accw0[hh] = fmaf(w2, x0, accw0[hh]);
                                    accw0[hh] = fmaf(w3, x1, accw0[hh]);
                                    accw0[hh] = fmaf(w4, x2, accw0[hh]);
                                }
                            }
                        }
                    }
                }
            }
        }
        __syncthreads();
    }

    if (dok) {
        float* Cn = C + ((size_t)s * NB + n) * CVOL + (size_t)d * (VALID * VALID);
        #pragma unroll
        for (int hh = 0; hh < 3; ++hh) {
            if (hh < 2 || tall) {
                int h = 2 * hg + hh;
                Cn[h * VALID + 2 * wq + 1] = acc[hh][0];
                Cn[h * VALID + 2 * wq + 2] = acc[hh][1];
                if (w0t) Cn[h * VALID] = accw0[hh];
            }
        }
    }
}

// Blocks 0..863: one wave per active cell (n, i<3, j<3, k<3); lane = p1-subcell;
// fused nsplit reduction; butterfly sum. Blocks 864..988: constant fill.
__global__ __launch_bounds__(64) void pool_kernel(const float* __restrict__ C,
                                                  const float* __restrict__ wsB,
                                                  float* __restrict__ out,
                                                  int nsplit) {
    const int b = blockIdx.x;
    const int l = threadIdx.x;
    const float B = wsB[0];

    if (b < 864) {
        const int n = b / 27;
        const int cell = b - n * 27;
        const int ci = cell / 9, cj = (cell / 3) % 3, ck = cell % 3;
        float v = 0.f;
        if (l < 27) {
            const int da = l / 9, db = (l / 3) % 3, dc = l % 3;
            const int pz = 3 * ci + da, py = 3 * cj + db, px = 3 * ck + dc;
            const float* Cn = C + (size_t)n * CVOL;
            float m = -INFINITY;
            #pragma unroll
            for (int dz = 0; dz < 2; ++dz)
            #pragma unroll
            for (int dy = 0; dy < 2; ++dy)
            #pragma unroll
            for (int dx = 0; dx < 2; ++dx) {
                int z = 2 * pz + dz, y = 2 * py + dy, xx = 2 * px + dx;
                float t;
                if (z < VALID && y < VALID && xx < VALID) {
                    size_t off = ((size_t)z * VALID + y) * VALID + xx;
                    float sum = 0.f;
                    for (int ss = 0; ss < nsplit; ++ss)
                        sum += Cn[(size_t)ss * NB * CVOL + off];
                    t = sum + B;
                } else {
                    t = B;
                }
                m = fmaxf(m, t);
            }
            v = m;
        }
        #pragma unroll
        for (int off = 32; off > 0; off >>= 1) v += __shfl_xor(v, off, 64);
        if (l == 0) out[n * 1000 + ci * 100 + cj * 10 + ck] = v;
    } else {
        const int fb = b - 864;           // 0..124
        #pragma unroll
        for (int t = 0; t < 4; ++t) {
            int idx = fb * 256 + 64 * t + l;
            if (idx < 32000) {
                int r = idx % 1000;
                int i = r / 100, j = (r / 10) % 10, k = r % 10;
                if (i >= 3 || j >= 3 || k >= 3) out[idx] = 27.f * B;
            }
        }
    }
}

extern "C" void kernel_launch(void* const* d_in, const int* in_sizes, int n_in,
                              void* d_out, int out_size, void* d_ws, size_t ws_size,
                              hipStream_t stream) {
    const float* x      = (const float*)d_in[0];
    const float* weight = (const float*)d_in[1];
    const float* bias   = (const float*)d_in[2];
    float* out = (float*)d_out;
    float* ws  = (float*)d_ws;
    float* weff = ws;
    float* wsB  = ws + 4000;
    float* C    = ws + 4096;

    int nsplit = 1;
    if      (ws_size >= (size_t)(4096 + 8 * NB * CVOL) * 4) nsplit = 8;
    else if (ws_size >= (size_t)(4096 + 4 * NB * CVOL) * 4) nsplit = 4;
    else if (ws_size >= (size_t)(4096 + 2 * NB * CVOL) * 4) nsplit = 2;
    int cpS = CIN / nsplit;

    prep_kernel<<<dim3(16), dim3(256), 0, stream>>>(weight, bias, ws);
    conv_kernel<<<dim3(nsplit * NB * 9), dim3(128), 0, stream>>>(x, weff, C, cpS);
    pool_kernel<<<dim3(989), dim3(64), 0, stream>>>(C, wsB, out, nsplit);
}

// Round 12
// 87.477 us; speedup vs baseline: 6.1555x; 1.5090x over previous
//
#include <hip/hip_runtime.h>
#include <math.h>

#define NB 32
#define CIN 32
#define DIM 32
#define KK 5
#define VALID 17
#define CVOL (VALID*VALID*VALID)   // 4913
#define PW 1024                    // plane words (32*32), linear, no padding
#define SLABF (7*PW + 4)           // +4 pad words for wq7 vb over-read at the last row

// ws layout (floats): [0,4000) w_eff ; [4000] B ; [4096, ...) C partials [nsplit][32][4913]

__global__ __launch_bounds__(256) void prep_kernel(const float* __restrict__ weight,
                                                   const float* __restrict__ bias,
                                                   float* __restrict__ ws) {
    int idx = blockIdx.x * 256 + threadIdx.x;
    if (idx < 4000) {
        float s = 0.f;
        #pragma unroll 8
        for (int co = 0; co < 64; ++co) s += weight[co * 4000 + idx];
        ws[idx] = s;
    }
    if (idx == 0) {
        float b = 0.f;
        for (int i = 0; i < 64; ++i) b += bias[i];
        ws[4000] = b;
    }
}

__device__ __forceinline__ void gload_lds16(const float* g, float* l) {
    __builtin_amdgcn_global_load_lds((const __attribute__((address_space(1))) void*)g,
                                     (__attribute__((address_space(3))) void*)l,
                                     16, 0, 0);
}

// Block = (split s, n, d-pair p). 128 threads: dq = tid>>6 (wave-uniform), hg = (tid>>3)&7, wq = tid&7.
// Thread outputs: d = 2p+dq; h = 2hg+hh (hg7: h14,15,16); w = 2wq+1, 2wq+2 (+ w=0 if wq==0).
// Slab: LINEAR f32 [pi 7][ih 32][iw 32]; pi = id-(4p-2); kd plane of d: pi = 2dq+kd.
// Staging: global_load_lds width 16 (no VGPR round-trip) — frees ~56 VGPRs vs pf[14],
// letting the compiler hoist ds_reads across FMA groups (the round-8 latency bottleneck).
// Linear rows: read quad = wq mod 8 -> conflict-free. OOB rows/taps are compile-pattern-skipped.
__global__ __launch_bounds__(128) void conv_kernel(const float* __restrict__ x,
                                                   const float* __restrict__ weff,
                                                   float* __restrict__ C,
                                                   int cpS) {
    __shared__ __align__(16) float slab[SLABF];
    const int b = blockIdx.x;
    const int s = b / (NB * 9);
    const int rem = b - s * (NB * 9);
    const int n = rem / 9;
    const int p = rem - n * 9;
    const int tid = threadIdx.x;
    const int dq = tid >> 6;          // wave index
    const int hg = (tid >> 3) & 7;
    const int wq = tid & 7;
    const int lane = tid & 63;
    const int d  = 2 * p + dq;
    const bool dok  = (d < VALID);
    const bool tall = (hg == 7);
    const bool w0t  = (wq == 0);

    // zero slab once: OOB planes (never staged) must read as 0
    for (int t = tid; t < SLABF / 4; t += 128) ((float4*)slab)[t] = make_float4(0.f, 0.f, 0.f, 0.f);
    __syncthreads();

    const int id0 = 4 * p - 2;
    const int cin0 = s * cpS;

    float acc[3][2] = {{0.f,0.f},{0.f,0.f},{0.f,0.f}};
    float accw0[3]  = {0.f, 0.f, 0.f};

    for (int ci = 0; ci < cpS; ++ci) {
        // stage: 28 slots (7 planes x 4 chunks of 1KB); wave wv issues slots [14wv,14wv+14)
        const float* xc = x + ((size_t)n * CIN + (cin0 + ci)) * (DIM * DIM * DIM);
        #pragma unroll
        for (int st = 0; st < 14; ++st) {
            int slot = dq * 14 + st;          // wave-uniform
            int pi = slot >> 2, c = slot & 3;
            int id = id0 + pi;
            if (id >= 0 && id < DIM) {        // wave-uniform guard
                gload_lds16(xc + (size_t)id * PW + c * 256 + lane * 4,
                            slab + pi * PW + c * 256);
            }
        }
        __syncthreads();   // drains vmcnt: staged data visible

        const float* wb = weff + (cin0 + ci) * 125;
        #pragma unroll
        for (int kd = 0; kd < KK; ++kd) {
            const float* plane = slab + (2 * dq + kd) * PW;
            #pragma unroll
            for (int j = 0; j < 9; ++j) {
                const int ih = 4 * hg + j - 2;
                if (((unsigned)ih < 32u) && (j <= 6 || tall)) {
                    const float* rp = plane + ih * 32 + 4 * wq;
                    const float4 va = *(const float4*)rp;
                    const float4 vb = *(const float4*)(rp + 4);  // wq7: next-row garbage, guarded below
                    #pragma unroll
                    for (int hh = 0; hh < 3; ++hh) {
                        const int kh = j - 2 * hh;
                        if (kh >= 0 && kh < KK) {
                            if (hh < 2 || tall) {
                                const float w0 = wb[kd * 25 + kh * 5 + 0];
                                const float w1 = wb[kd * 25 + kh * 5 + 1];
                                const float w2 = wb[kd * 25 + kh * 5 + 2];
                                const float w3 = wb[kd * 25 + kh * 5 + 3];
                                const float w4 = wb[kd * 25 + kh * 5 + 4];
                                acc[hh][0] = fmaf(w0, va.x, acc[hh][0]);
                                acc[hh][1] = fmaf(w0, va.z, acc[hh][1]);
                                acc[hh][0] = fmaf(w1, va.y, acc[hh][0]);
                                acc[hh][1] = fmaf(w1, va.w, acc[hh][1]);
                                acc[hh][0] = fmaf(w2, va.z, acc[hh][0]);
                                acc[hh][0] = fmaf(w3, va.w, acc[hh][0]);
                                if (wq < 7) {   // wq7's vb taps are true zero-pad (iw>=32): skip
                                    acc[hh][0] = fmaf(w4, vb.x, acc[hh][0]);
                                    acc[hh][1] = fmaf(w2, vb.x, acc[hh][1]);
                                    acc[hh][1] = fmaf(w3, vb.y, acc[hh][1]);
                                    acc[hh][1] = fmaf(w4, vb.z, acc[hh][1]);
                                }
                                if (w0t) {      // w=0: kw 2,3,4 hit iw 0,1,2
                                    accw0[hh] = fmaf(w2, va.x, accw0[hh]);
                                    accw0[hh] = fmaf(w3, va.y, accw0[hh]);
                                    accw0[hh] = fmaf(w4, va.z, accw0[hh]);
                                }
                            }
                        }
                    }
                }
            }
        }
        __syncthreads();   // WAR: next stage overwrites slab
    }

    if (dok) {
        float* Cn = C + ((size_t)s * NB + n) * CVOL + (size_t)d * (VALID * VALID);
        #pragma unroll
        for (int hh = 0; hh < 3; ++hh) {
            if (hh < 2 || tall) {
                int h = 2 * hg + hh;
                Cn[h * VALID + 2 * wq + 1] = acc[hh][0];
                Cn[h * VALID + 2 * wq + 2] = acc[hh][1];
                if (w0t) Cn[h * VALID] = accw0[hh];
            }
        }
    }
}

// Blocks 0..863: one wave per active cell (n, i<3, j<3, k<3); lane = p1-subcell;
// fused nsplit reduction; butterfly sum. Blocks 864..988: constant fill.
__global__ __launch_bounds__(64) void pool_kernel(const float* __restrict__ C,
                                                  const float* __restrict__ wsB,
                                                  float* __restrict__ out,
                                                  int nsplit) {
    const int b = blockIdx.x;
    const int l = threadIdx.x;
    const float B = wsB[0];

    if (b < 864) {
        const int n = b / 27;
        const int cell = b - n * 27;
        const int ci = cell / 9, cj = (cell / 3) % 3, ck = cell % 3;
        float v = 0.f;
        if (l < 27) {
            const int da = l / 9, db = (l / 3) % 3, dc = l % 3;
            const int pz = 3 * ci + da, py = 3 * cj + db, px = 3 * ck + dc;
            const float* Cn = C + (size_t)n * CVOL;
            float m = -INFINITY;
            #pragma unroll
            for (int dz = 0; dz < 2; ++dz)
            #pragma unroll
            for (int dy = 0; dy < 2; ++dy)
            #pragma unroll
            for (int dx = 0; dx < 2; ++dx) {
                int z = 2 * pz + dz, y = 2 * py + dy, xx = 2 * px + dx;
                float t;
                if (z < VALID && y < VALID && xx < VALID) {
                    size_t off = ((size_t)z * VALID + y) * VALID + xx;
                    float sum = 0.f;
                    for (int ss = 0; ss < nsplit; ++ss)
                        sum += Cn[(size_t)ss * NB * CVOL + off];
                    t = sum + B;
                } else {
                    t = B;
                }
                m = fmaxf(m, t);
            }
            v = m;
        }
        #pragma unroll
        for (int off = 32; off > 0; off >>= 1) v += __shfl_xor(v, off, 64);
        if (l == 0) out[n * 1000 + ci * 100 + cj * 10 + ck] = v;
    } else {
        const int fb = b - 864;           // 0..124
        #pragma unroll
        for (int t = 0; t < 4; ++t) {
            int idx = fb * 256 + 64 * t + l;
            if (idx < 32000) {
                int r = idx % 1000;
                int i = r / 100, j = (r / 10) % 10, k = r % 10;
                if (i >= 3 || j >= 3 || k >= 3) out[idx] = 27.f * B;
            }
        }
    }
}

extern "C" void kernel_launch(void* const* d_in, const int* in_sizes, int n_in,
                              void* d_out, int out_size, void* d_ws, size_t ws_size,
                              hipStream_t stream) {
    const float* x      = (const float*)d_in[0];
    const float* weight = (const float*)d_in[1];
    const float* bias   = (const float*)d_in[2];
    float* out = (float*)d_out;
    float* ws  = (float*)d_ws;
    float* weff = ws;
    float* wsB  = ws + 4000;
    float* C    = ws + 4096;

    int nsplit = 1;
    if      (ws_size >= (size_t)(4096 + 8 * NB * CVOL) * 4) nsplit = 8;
    else if (ws_size >= (size_t)(4096 + 4 * NB * CVOL) * 4) nsplit = 4;
    else if (ws_size >= (size_t)(4096 + 2 * NB * CVOL) * 4) nsplit = 2;
    int cpS = CIN / nsplit;

    prep_kernel<<<dim3(16), dim3(256), 0, stream>>>(weight, bias, ws);
    conv_kernel<<<dim3(nsplit * NB * 9), dim3(128), 0, stream>>>(x, weff, C, cpS);
    pool_kernel<<<dim3(989), dim3(64), 0, stream>>>(C, wsB, out, nsplit);
}